// Round 13
// baseline (113.691 us; speedup 1.0000x reference)
//
#include <hip/hip_runtime.h>
#include <stdint.h>

#define N 4096
#define D 1024            // elements per row; fp8 => 1024 bytes per row
#define MARGIN 0.1f
#define BM 64
#define BN 128
#define BKB 128           // K-slab per tile in fp8 bytes (=128 elements)
#define SCALE_ONE 0x7F    // e8m0 encoding of 1.0
#define ASZ (BM * BKB)    // 8 KB per A buffer
#define BSZ (BN * BKB)    // 16 KB per B buffer

typedef __attribute__((ext_vector_type(4))) float f32x4;
typedef __attribute__((ext_vector_type(8))) int i32x8;

// Kernel 1: one wave per row (4 rows/block): fp32 norms + diagonal dot,
// butterfly shfl_xor reduce, write normalized rows as OCP fp8 e4m3.
// Block 0 zeroes d_out. d_i stays fp32 (the only correlated error path).
__global__ __launch_bounds__(256) void prep_kernel(
    const float* __restrict__ W, const float* __restrict__ O,
    uint8_t* __restrict__ Wn, uint8_t* __restrict__ On,
    float* __restrict__ dvec, float* __restrict__ out) {
  const int wv = threadIdx.x >> 6, ln = threadIdx.x & 63;
  const int row = blockIdx.x * 4 + wv;
  if (blockIdx.x == 0 && threadIdx.x == 0) *out = 0.0f;
  const float4* Wr = (const float4*)(W + (size_t)row * D);
  const float4* Or = (const float4*)(O + (size_t)row * D);
  float4 w[4], o[4];
  float sw = 0.f, so = 0.f, sd = 0.f;
  #pragma unroll
  for (int c = 0; c < 4; ++c) {
    w[c] = Wr[ln + c * 64];
    o[c] = Or[ln + c * 64];
    sw += w[c].x * w[c].x + w[c].y * w[c].y + w[c].z * w[c].z + w[c].w * w[c].w;
    so += o[c].x * o[c].x + o[c].y * o[c].y + o[c].z * o[c].z + o[c].w * o[c].w;
    sd += w[c].x * o[c].x + w[c].y * o[c].y + w[c].z * o[c].z + w[c].w * o[c].w;
  }
  #pragma unroll
  for (int off = 1; off < 64; off <<= 1) {
    sw += __shfl_xor(sw, off, 64);
    so += __shfl_xor(so, off, 64);
    sd += __shfl_xor(sd, off, 64);
  }
  const float inw = 1.0f / sqrtf(sw);
  const float ino = 1.0f / sqrtf(so);
  if (ln == 0) dvec[row] = sd * inw * ino;
  int* Wo = (int*)(Wn + (size_t)row * D);
  int* Oo = (int*)(On + (size_t)row * D);
  #pragma unroll
  for (int c = 0; c < 4; ++c) {
    int pw = __builtin_amdgcn_cvt_pk_fp8_f32(w[c].x * inw, w[c].y * inw, 0, false);
    pw = __builtin_amdgcn_cvt_pk_fp8_f32(w[c].z * inw, w[c].w * inw, pw, true);
    int po = __builtin_amdgcn_cvt_pk_fp8_f32(o[c].x * ino, o[c].y * ino, 0, false);
    po = __builtin_amdgcn_cvt_pk_fp8_f32(o[c].z * ino, o[c].w * ino, po, true);
    Wo[ln + c * 64] = pw;
    Oo[ln + c * 64] = po;
  }
}

// Kernel 2: 64x128-tile MX-fp8 (K=128) GEMM, DOUBLE-BUFFERED LDS.
// R12 evidence chain: wall invariant to occupancy (R8), DS bytes (R9),
// and MFMA issue count (R12 ~= R9 by total-time accounting) => the
// binding constraint is the per-slab vmcnt(0)+barrier drain: ~900cyc
// staging latency exposed 8x per block against only ~400cyc of compute.
// R13: prefetch slab kt+1 into the alternate buffer AFTER the barrier,
// so the compiler's forced vmcnt(0)-before-barrier drains loads that
// have had a full slab's compute in flight. One barrier per slab.
// LDS 2x24KB=48KB -> still 3 blocks/CU. kt loop stays unroll 1 (R11/R12:
// unrolling hoists 48 staging addresses -> VGPR 220 -> 2 blocks/CU).
// Scaled-MFMA layout + e8m0 0x7F HW-verified (R10-R12 absmax 0.0).
__global__ __launch_bounds__(256) void gemm_loss_kernel(
    const uint8_t* __restrict__ Wn, const uint8_t* __restrict__ On,
    const float* __restrict__ dvec, float* __restrict__ out) {
  __shared__ __align__(16) uint8_t ldsA[2 * ASZ];  // 16 KB
  __shared__ __align__(16) uint8_t ldsB[2 * BSZ];  // 32 KB
  const int bx = blockIdx.x, by = blockIdx.y;
  const int t = threadIdx.x;
  const int wv = t >> 6, ln = t & 63;
  const int wm = wv >> 1, wn = wv & 1;   // 2x2 wave grid; wave = 32x64 of C
  const int lrow = ln & 15;
  const int quad = ln >> 4;
  const int l7 = lrow & 7;               // == rr&7 == cc&7 for fragment rows

  f32x4 acc[2][4] = {};

  const uint8_t* Ag = Wn + (size_t)(by * BM) * D;
  const uint8_t* Bg = On + (size_t)(bx * BN) * D;

  // This thread's fixed staging slots (granule index -> row, swizzled col)
  const int rA0 = t >> 3,           cA0 = (((t & 7) ^ (rA0 & 7)) << 4);
  const int rA1 = (t + 256) >> 3,   cA1 = ((((t + 256) & 7) ^ (rA1 & 7)) << 4);

  // swizzled byte offsets of this lane's two 16B granules within a row
  const int goff0 = (((2 * quad) ^ l7) << 4);
  const int goff1 = (((2 * quad + 1) ^ l7) << 4);
  const int aRow0 = (wm * 32 + lrow) * BKB;        // mi=0 row offset
  const int bRow = (wn * 64 + lrow) * BKB;

  // ---- prologue: stage slab 0 into buffer 0 ----
  {
    __builtin_amdgcn_global_load_lds(
        (const __attribute__((address_space(1))) void*)(Ag + (size_t)rA0 * D + cA0),
        (__attribute__((address_space(3))) void*)(ldsA + t * 16), 16, 0, 0);
    __builtin_amdgcn_global_load_lds(
        (const __attribute__((address_space(1))) void*)(Ag + (size_t)rA1 * D + cA1),
        (__attribute__((address_space(3))) void*)(ldsA + (t + 256) * 16), 16, 0, 0);
    #pragma unroll
    for (int c = 0; c < 4; ++c) {
      const int g = c * 256 + t;
      const int r = g >> 3;
      const int col = (((g & 7) ^ (r & 7)) << 4);
      __builtin_amdgcn_global_load_lds(
          (const __attribute__((address_space(1))) void*)(Bg + (size_t)r * D + col),
          (__attribute__((address_space(3))) void*)(ldsB + g * 16), 16, 0, 0);
    }
  }

  #pragma unroll 1
  for (int kt = 0; kt < D / BKB; ++kt) {   // 8 slabs, NOT unrolled
    const int cur = kt & 1;
    __syncthreads();  // drains staging of slab kt (vmcnt(0)) + WAR guard

    // ---- prefetch slab kt+1 into the other buffer (in flight all slab) ----
    if (kt < D / BKB - 1) {
      const size_t kb = (size_t)(kt + 1) * BKB;
      const int nxt = cur ^ 1;
      __builtin_amdgcn_global_load_lds(
          (const __attribute__((address_space(1))) void*)(Ag + (size_t)rA0 * D + kb + cA0),
          (__attribute__((address_space(3))) void*)(ldsA + nxt * ASZ + t * 16), 16, 0, 0);
      __builtin_amdgcn_global_load_lds(
          (const __attribute__((address_space(1))) void*)(Ag + (size_t)rA1 * D + kb + cA1),
          (__attribute__((address_space(3))) void*)(ldsA + nxt * ASZ + (t + 256) * 16), 16, 0, 0);
      #pragma unroll
      for (int c = 0; c < 4; ++c) {
        const int g = c * 256 + t;
        const int r = g >> 3;
        const int col = (((g & 7) ^ (r & 7)) << 4);
        __builtin_amdgcn_global_load_lds(
            (const __attribute__((address_space(1))) void*)(Bg + (size_t)r * D + kb + col),
            (__attribute__((address_space(3))) void*)(ldsB + nxt * BSZ + g * 16), 16, 0, 0);
      }
    }

    // ---- compute slab kt from buffer cur: aF[2] resident, bF streamed ----
    const uint8_t* aB = ldsA + cur * ASZ + aRow0;
    const uint8_t* bB = ldsB + cur * BSZ + bRow;
    i32x8 aF[2];
    {
      const int4 lo0 = *(const int4*)(aB + goff0);
      const int4 hi0 = *(const int4*)(aB + goff1);
      aF[0] = (i32x8){lo0.x, lo0.y, lo0.z, lo0.w, hi0.x, hi0.y, hi0.z, hi0.w};
      const int4 lo1 = *(const int4*)(aB + 16 * BKB + goff0);
      const int4 hi1 = *(const int4*)(aB + 16 * BKB + goff1);
      aF[1] = (i32x8){lo1.x, lo1.y, lo1.z, lo1.w, hi1.x, hi1.y, hi1.z, hi1.w};
    }
    #pragma unroll
    for (int ni = 0; ni < 4; ++ni) {
      const uint8_t* base = bB + ni * 16 * BKB;
      const int4 lo = *(const int4*)(base + goff0);
      const int4 hi = *(const int4*)(base + goff1);
      const i32x8 bF = (i32x8){lo.x, lo.y, lo.z, lo.w, hi.x, hi.y, hi.z, hi.w};
      acc[0][ni] = __builtin_amdgcn_mfma_scale_f32_16x16x128_f8f6f4(
          aF[0], bF, acc[0][ni], 0, 0, 0, SCALE_ONE, 0, SCALE_ONE);
      acc[1][ni] = __builtin_amdgcn_mfma_scale_f32_16x16x128_f8f6f4(
          aF[1], bF, acc[1][ni], 0, 0, 0, SCALE_ONE, 0, SCALE_ONE);
    }
  }

  // Epilogue: C/D layout col=lane&15, row=quad*4+reg (shape-determined,
  // dtype/FMT-independent — m89/m121/m127; R10-R12 absmax=0 confirmed)
  float lsum = 0.0f;
  #pragma unroll
  for (int mi = 0; mi < 2; ++mi) {
    const int gibase = by * BM + wm * 32 + mi * 16 + quad * 4;
    #pragma unroll
    for (int r = 0; r < 4; ++r) {
      const int gi = gibase + r;
      const float di = dvec[gi];  // fp32 diagonal (accurate)
      #pragma unroll
      for (int ni = 0; ni < 4; ++ni) {
        const int gj = bx * BN + wn * 64 + ni * 16 + lrow;
        const float s = acc[mi][ni][r];
        lsum += (gi == gj) ? (1.0f - s) : fmaxf(MARGIN - s + di, 0.0f);
      }
    }
  }
  #pragma unroll
  for (int off = 32; off; off >>= 1) lsum += __shfl_down(lsum, off, 64);
  __shared__ float bsum[4];
  if (ln == 0) bsum[wv] = lsum;
  __syncthreads();
  if (t == 0) {
    const float tot = (bsum[0] + bsum[1] + bsum[2] + bsum[3]) *
                      (1.0f / ((float)N * (float)N));
    atomicAdd(out, tot);
  }
}

extern "C" void kernel_launch(void* const* d_in, const int* in_sizes, int n_in,
                              void* d_out, int out_size, void* d_ws, size_t ws_size,
                              hipStream_t stream) {
  const float* W = (const float*)d_in[0];  // wsi_embeddings (N,1,D)
  const float* O = (const float*)d_in[1];  // omic_embeddings (N,1,D)
  uint8_t* Wn = (uint8_t*)d_ws;                     // 4 MB fp8
  uint8_t* On = Wn + (size_t)N * D;                 // 4 MB fp8
  float* dvec = (float*)(On + (size_t)N * D);       // 16 KB
  float* out = (float*)d_out;

  prep_kernel<<<N / 4, 256, 0, stream>>>(W, O, Wn, On, dvec, out);
  dim3 grid(N / BN, N / BM);  // (32, 64) = 2048 blocks
  gemm_loss_kernel<<<grid, 256, 0, stream>>>(Wn, On, dvec, out);
}

// Round 14
// 113.640 us; speedup vs baseline: 1.0004x; 1.0004x over previous
//
#include <hip/hip_runtime.h>
#include <stdint.h>

#define N 4096
#define D 1024            // elements per row; fp8 => 1024 bytes per row
#define MARGIN 0.1f
#define BM 64
#define BN 128
#define BKB 128           // K-slab per tile in fp8 bytes (=128 elements)
#define SCALE_ONE 0x7F    // e8m0 encoding of 1.0

typedef __attribute__((ext_vector_type(4))) float f32x4;
typedef __attribute__((ext_vector_type(8))) int i32x8;

// Kernel 1: one wave per row (4 rows/block): fp32 norms + diagonal dot,
// butterfly shfl_xor reduce, write normalized rows as OCP fp8 e4m3.
// Block 0 zeroes d_out. d_i stays fp32 (the only correlated error path).
__global__ __launch_bounds__(256) void prep_kernel(
    const float* __restrict__ W, const float* __restrict__ O,
    uint8_t* __restrict__ Wn, uint8_t* __restrict__ On,
    float* __restrict__ dvec, float* __restrict__ out) {
  const int wv = threadIdx.x >> 6, ln = threadIdx.x & 63;
  const int row = blockIdx.x * 4 + wv;
  if (blockIdx.x == 0 && threadIdx.x == 0) *out = 0.0f;
  const float4* Wr = (const float4*)(W + (size_t)row * D);
  const float4* Or = (const float4*)(O + (size_t)row * D);
  float4 w[4], o[4];
  float sw = 0.f, so = 0.f, sd = 0.f;
  #pragma unroll
  for (int c = 0; c < 4; ++c) {
    w[c] = Wr[ln + c * 64];
    o[c] = Or[ln + c * 64];
    sw += w[c].x * w[c].x + w[c].y * w[c].y + w[c].z * w[c].z + w[c].w * w[c].w;
    so += o[c].x * o[c].x + o[c].y * o[c].y + o[c].z * o[c].z + o[c].w * o[c].w;
    sd += w[c].x * o[c].x + w[c].y * o[c].y + w[c].z * o[c].z + w[c].w * o[c].w;
  }
  #pragma unroll
  for (int off = 1; off < 64; off <<= 1) {
    sw += __shfl_xor(sw, off, 64);
    so += __shfl_xor(so, off, 64);
    sd += __shfl_xor(sd, off, 64);
  }
  const float inw = 1.0f / sqrtf(sw);
  const float ino = 1.0f / sqrtf(so);
  if (ln == 0) dvec[row] = sd * inw * ino;
  int* Wo = (int*)(Wn + (size_t)row * D);
  int* Oo = (int*)(On + (size_t)row * D);
  #pragma unroll
  for (int c = 0; c < 4; ++c) {
    int pw = __builtin_amdgcn_cvt_pk_fp8_f32(w[c].x * inw, w[c].y * inw, 0, false);
    pw = __builtin_amdgcn_cvt_pk_fp8_f32(w[c].z * inw, w[c].w * inw, pw, true);
    int po = __builtin_amdgcn_cvt_pk_fp8_f32(o[c].x * ino, o[c].y * ino, 0, false);
    po = __builtin_amdgcn_cvt_pk_fp8_f32(o[c].z * ino, o[c].w * ino, po, true);
    Wo[ln + c * 64] = pw;
    Oo[ln + c * 64] = po;
  }
}

// Kernel 2: 64x128-tile MX-fp8 (K=128) GEMM — R12 body verbatim, plus an
// XCD-AWARE BLOCK REMAP.
// R14 thesis: all CU-internal levers were neutral (R8 occupancy, R9/R12
// MFMA rate, R13 dbuf). Staged bytes = 384 MB over ~43us = ~9 TB/s = L3
// service rate. Old 2D grid: XCD = id%8 = bx%8 -> each XCD cycles ALL 64
// A-tiles (4 MB) through its 4 MB L2 -> LRU thrash, 0% A hits, all L3.
// Remap: XCD x owns by-band [x*8,x*8+8) (A band 512 KB resident) and
// walks bx in groups of 8 (B group 1 MB) -> ~2 MB concurrent working
// set < 4 MB L2. Re-reads (48 MB/XCD) move from L3 (~9 TB/s chip) to
// L2 (~4.3 TB/s per XCD). Mapping is a perf heuristic only (G16-safe).
__global__ __launch_bounds__(256) void gemm_loss_kernel(
    const uint8_t* __restrict__ Wn, const uint8_t* __restrict__ On,
    const float* __restrict__ dvec, float* __restrict__ out) {
  __shared__ __align__(16) uint8_t ldsA[BM * BKB];  // 8 KB
  __shared__ __align__(16) uint8_t ldsB[BN * BKB];  // 16 KB
  // --- XCD-aware remap (assumes round-robin id%8 -> XCD) ---
  const int id = blockIdx.x;            // 0..2047
  const int xcd = id & 7;
  const int local = id >> 3;            // 0..255 within XCD
  const int g = local >> 6;             // bx group 0..3
  const int by = xcd * 8 + ((local >> 3) & 7);   // 0..63
  const int bx = g * 8 + (local & 7);            // 0..31
  const int t = threadIdx.x;
  const int wv = t >> 6, ln = t & 63;
  const int wm = wv >> 1, wn = wv & 1;   // 2x2 wave grid; wave = 32x64 of C
  const int lrow = ln & 15;
  const int quad = ln >> 4;
  const int l7 = lrow & 7;               // == rr&7 == cc&7 for fragment rows

  f32x4 acc[2][4] = {};

  const int rA0 = t >> 3,          cA0 = (((t & 7) ^ (rA0 & 7)) << 4);
  const int rA1 = (t + 256) >> 3,  cA1 = ((((t + 256) & 7) ^ (rA1 & 7)) << 4);
  const uint8_t* Ag = Wn + (size_t)(by * BM) * D;
  const uint8_t* Bg = On + (size_t)(bx * BN) * D;

  // swizzled byte offsets of this lane's two 16B granules within a row
  const int goff0 = (((2 * quad) ^ l7) << 4);
  const int goff1 = (((2 * quad + 1) ^ l7) << 4);
  const uint8_t* aBase0 = ldsA + (wm * 32 + lrow) * BKB;          // mi=0
  const uint8_t* aBase1 = aBase0 + 16 * BKB;                      // mi=1
  const uint8_t* bBase = ldsB + (wn * 64 + lrow) * BKB;

  #pragma unroll 1
  for (int kt = 0; kt < D / BKB; ++kt) {           // 8 slabs, NOT unrolled
    const size_t kb = (size_t)kt * BKB;
    // A-tile: 64 rows x 128 B = 512 granules(16B) = 2 rounds of 256 threads
    __builtin_amdgcn_global_load_lds(
        (const __attribute__((address_space(1))) void*)(Ag + (size_t)rA0 * D + kb + cA0),
        (__attribute__((address_space(3))) void*)(ldsA + t * 16), 16, 0, 0);
    __builtin_amdgcn_global_load_lds(
        (const __attribute__((address_space(1))) void*)(Ag + (size_t)rA1 * D + kb + cA1),
        (__attribute__((address_space(3))) void*)(ldsA + (t + 256) * 16), 16, 0, 0);
    // B-tile: 128 rows x 128 B = 1024 granules = 4 rounds
    #pragma unroll
    for (int c = 0; c < 4; ++c) {
      const int gg = c * 256 + t;
      const int r = gg >> 3;
      const int gi = gg & 7;
      __builtin_amdgcn_global_load_lds(
          (const __attribute__((address_space(1))) void*)(Bg + (size_t)r * D + kb + ((gi ^ (r & 7)) << 4)),
          (__attribute__((address_space(3))) void*)(ldsB + gg * 16), 16, 0, 0);
    }
    __syncthreads();

    // One K=128 step per slab: aF[2] resident, bF streamed (8 scaled MFMAs).
    i32x8 aF[2];
    {
      const int4 lo0 = *(const int4*)(aBase0 + goff0);
      const int4 hi0 = *(const int4*)(aBase0 + goff1);
      aF[0] = (i32x8){lo0.x, lo0.y, lo0.z, lo0.w, hi0.x, hi0.y, hi0.z, hi0.w};
      const int4 lo1 = *(const int4*)(aBase1 + goff0);
      const int4 hi1 = *(const int4*)(aBase1 + goff1);
      aF[1] = (i32x8){lo1.x, lo1.y, lo1.z, lo1.w, hi1.x, hi1.y, hi1.z, hi1.w};
    }
    #pragma unroll
    for (int ni = 0; ni < 4; ++ni) {
      const uint8_t* base = bBase + ni * 16 * BKB;
      const int4 lo = *(const int4*)(base + goff0);
      const int4 hi = *(const int4*)(base + goff1);
      const i32x8 bF = (i32x8){lo.x, lo.y, lo.z, lo.w, hi.x, hi.y, hi.z, hi.w};
      acc[0][ni] = __builtin_amdgcn_mfma_scale_f32_16x16x128_f8f6f4(
          aF[0], bF, acc[0][ni], 0, 0, 0, SCALE_ONE, 0, SCALE_ONE);
      acc[1][ni] = __builtin_amdgcn_mfma_scale_f32_16x16x128_f8f6f4(
          aF[1], bF, acc[1][ni], 0, 0, 0, SCALE_ONE, 0, SCALE_ONE);
    }
    __syncthreads();
  }

  // Epilogue: C/D layout col=lane&15, row=quad*4+reg (shape-determined,
  // dtype/FMT-independent — m89/m121/m127; R10-R13 absmax=0 confirmed)
  float lsum = 0.0f;
  #pragma unroll
  for (int mi = 0; mi < 2; ++mi) {
    const int gibase = by * BM + wm * 32 + mi * 16 + quad * 4;
    #pragma unroll
    for (int r = 0; r < 4; ++r) {
      const int gi = gibase + r;
      const float di = dvec[gi];  // fp32 diagonal (accurate)
      #pragma unroll
      for (int ni = 0; ni < 4; ++ni) {
        const int gj = bx * BN + wn * 64 + ni * 16 + lrow;
        const float s = acc[mi][ni][r];
        lsum += (gi == gj) ? (1.0f - s) : fmaxf(MARGIN - s + di, 0.0f);
      }
    }
  }
  #pragma unroll
  for (int off = 32; off; off >>= 1) lsum += __shfl_down(lsum, off, 64);
  __shared__ float bsum[4];
  if (ln == 0) bsum[wv] = lsum;
  __syncthreads();
  if (t == 0) {
    const float tot = (bsum[0] + bsum[1] + bsum[2] + bsum[3]) *
                      (1.0f / ((float)N * (float)N));
    atomicAdd(out, tot);
  }
}

extern "C" void kernel_launch(void* const* d_in, const int* in_sizes, int n_in,
                              void* d_out, int out_size, void* d_ws, size_t ws_size,
                              hipStream_t stream) {
  const float* W = (const float*)d_in[0];  // wsi_embeddings (N,1,D)
  const float* O = (const float*)d_in[1];  // omic_embeddings (N,1,D)
  uint8_t* Wn = (uint8_t*)d_ws;                     // 4 MB fp8
  uint8_t* On = Wn + (size_t)N * D;                 // 4 MB fp8
  float* dvec = (float*)(On + (size_t)N * D);       // 16 KB
  float* out = (float*)d_out;

  prep_kernel<<<N / 4, 256, 0, stream>>>(W, O, Wn, On, dvec, out);
  gemm_loss_kernel<<<(N / BN) * (N / BM), 256, 0, stream>>>(Wn, On, dvec, out);
}